// Round 4
// baseline (177.534 us; speedup 1.0000x reference)
//
#include <hip/hip_runtime.h>

// ---------------------------------------------------------------------------
// CausalSelfAttentionHead: B=8, S=2048, E=1024, H=64, scale = 1/H (NOT 1/sqrt)
// k0 prep_w : W fp32 [1024][64] -> Wt bf16 [192][1024]
// k1 proj   : BM=32, A-only LDS dbuf (8KB), B-frags DIRECT from L2 (reg-dbuf
//             one chunk ahead), A global->reg prefetch two chunks ahead.
// k2 attn   : flash w/o max-subtraction, M=16 strips paired (j,127-j),
//             grid 512 (2 blocks/CU), K 2-deep reg dbuf, exp-stage covers V
//             L2 latency, 2-slot LDS P-transpose pipeline.
// ws: Wt @0, qw @0x60000, kw @0x260000, vT @0x460000 (6.4MB total)
// ---------------------------------------------------------------------------

typedef __bf16 bf16;
typedef bf16 bf16x8 __attribute__((ext_vector_type(8)));
typedef bf16 bf16x4 __attribute__((ext_vector_type(4)));
typedef float v4f __attribute__((ext_vector_type(4)));

#define MFMA_BF16 __builtin_amdgcn_mfma_f32_16x16x32_bf16

constexpr int SEQ = 2048, EDIM = 1024, HDIM = 64;
constexpr float SCALE_L2E = 1.4426950408889634f / 64.0f;  // log2(e)/head_size

// ---------------- kernel 0: weight transpose + cvt -------------------------
__global__ __launch_bounds__(256) void prep_w_kernel(
    const float* __restrict__ Wq, const float* __restrict__ Wk,
    const float* __restrict__ Wv, bf16* __restrict__ Wt) {
  int mat = blockIdx.x >> 5, kseg = blockIdx.x & 31;
  const float* src = mat == 0 ? Wq : (mat == 1 ? Wk : Wv);
  int n = threadIdx.x & 63;
  int k0 = kseg * 32 + (threadIdx.x >> 6) * 8;
  bf16x8 v;
#pragma unroll
  for (int j = 0; j < 8; ++j)
    v[j] = (bf16)src[(k0 + j) * 64 + n];
  *reinterpret_cast<bf16x8*>(Wt + (size_t)(mat * 64 + n) * EDIM + k0) = v;
}

// ---------------- kernel 1: fused QKV projection (no B staging) ------------
// grid 512 (BM=32), block 256 (4 waves): wave w -> n-cols 48w..48w+47.
__global__ __launch_bounds__(256) void proj_kernel(
    const float* __restrict__ x, const bf16* __restrict__ Wt,
    bf16* __restrict__ qw, bf16* __restrict__ kw, bf16* __restrict__ vT) {
  __shared__ __align__(16) bf16 As[2][32][72];  // 8 KB only

  const int t = threadIdx.x;
  const int m0 = blockIdx.x * 32;
  const int wv = t >> 6, lane = t & 63, quad = lane >> 4, l16 = lane & 15;
  const int ar = t >> 3, ac = (t & 7) * 8;  // A-commit row/col (8 bf16/thread)

  v4f acc[2][3] = {};
  float4 aReg[2][2];   // [slot][2 float4] : two-chunk-deep A prefetch
  bf16x8 bReg[2][6];   // [slot][ks*3+ni]  : one-chunk-deep B fragments

  auto loadA = [&](int kk, int slot) {
    const float* p = x + (size_t)(m0 + ar) * EDIM + kk * 64 + ac;
    aReg[slot][0] = *reinterpret_cast<const float4*>(p);
    aReg[slot][1] = *reinterpret_cast<const float4*>(p + 4);
  };
  auto loadB = [&](int kk, int slot) {
#pragma unroll
    for (int ks = 0; ks < 2; ++ks)
#pragma unroll
      for (int ni = 0; ni < 3; ++ni)
        bReg[slot][ks * 3 + ni] = *reinterpret_cast<const bf16x8*>(
            Wt + (size_t)(48 * wv + 16 * ni + l16) * EDIM + kk * 64 +
            32 * ks + 8 * quad);
  };

  loadA(0, 0);
  loadA(1, 1);
  loadB(0, 0);

#pragma unroll 2
  for (int kk = 0; kk < 16; ++kk) {
    const int buf = kk & 1;
    {  // commit A chunk kk (regs loaded 2 iterations ago)
      bf16x8 h8;
#pragma unroll
      for (int e = 0; e < 4; ++e) {
        h8[e] = (bf16)(&aReg[buf][0].x)[e];
        h8[4 + e] = (bf16)(&aReg[buf][1].x)[e];
      }
      *reinterpret_cast<bf16x8*>(&As[buf][ar][ac]) = h8;
    }
    __syncthreads();
    if (kk + 2 < 16) loadA(kk + 2, buf);
    if (kk + 1 < 16) loadB(kk + 1, buf ^ 1);

    bf16x8 af[2][2];
#pragma unroll
    for (int mi = 0; mi < 2; ++mi)
#pragma unroll
      for (int ks = 0; ks < 2; ++ks)
        af[mi][ks] = *reinterpret_cast<const bf16x8*>(
            &As[buf][16 * mi + l16][32 * ks + 8 * quad]);
#pragma unroll
    for (int ks = 0; ks < 2; ++ks)
#pragma unroll
      for (int mi = 0; mi < 2; ++mi)
#pragma unroll
        for (int ni = 0; ni < 3; ++ni)
          acc[mi][ni] =
              MFMA_BF16(af[mi][ks], bReg[buf][ks * 3 + ni], acc[mi][ni], 0, 0, 0);
    __syncthreads();  // reads of As[buf] done before commit of kk+2 (same buf)
  }

#pragma unroll
  for (int mi = 0; mi < 2; ++mi) {
    const int token0 = m0 + 16 * mi + 4 * quad;
#pragma unroll
    for (int ni = 0; ni < 3; ++ni) {
      int n = 48 * wv + 16 * ni + l16;
      if (n < 64) {
#pragma unroll
        for (int r = 0; r < 4; ++r)
          qw[(size_t)(token0 + r) * HDIM + n] = (bf16)acc[mi][ni][r];
      } else if (n < 128) {
#pragma unroll
        for (int r = 0; r < 4; ++r)
          kw[(size_t)(token0 + r) * HDIM + (n - 64)] = (bf16)acc[mi][ni][r];
      } else {
        int b = token0 >> 11, s0 = token0 & 2047;
        bf16x4 pk = {(bf16)acc[mi][ni][0], (bf16)acc[mi][ni][1],
                     (bf16)acc[mi][ni][2], (bf16)acc[mi][ni][3]};
        *reinterpret_cast<bf16x4*>(
            vT + ((size_t)(b * 64 + (n - 128))) * SEQ + s0) = pk;
      }
    }
  }
}

// ---------------- kernel 2: pipelined flash attention (M=16) ---------------
// grid 512 = 64 strip-pairs x 8 batches; block 256 = 4 waves;
// strips of 16 rows, 64-key tiles; wave w takes tiles jt == w (mod 4).
__global__ __launch_bounds__(256) void attn_kernel(
    const bf16* __restrict__ qw, const bf16* __restrict__ kw,
    const bf16* __restrict__ vT, float* __restrict__ out) {
  const int batch = blockIdx.x & 7;
  const int pi = blockIdx.x >> 3;  // 0..63
  const int w = threadIdx.x >> 6;
  const int lane = threadIdx.x & 63;
  const int quad = lane >> 4, l16 = lane & 15;

  __shared__ __align__(16) bf16 p_lds[4][2][16][68];
  __shared__ __align__(16) float o_lds[3][16][68];
  __shared__ float l_lds[3][16];

  const bf16* qB = qw + (size_t)batch * SEQ * HDIM;
  const bf16* kB = kw + (size_t)batch * SEQ * HDIM;
  const bf16* vB = vT + (size_t)batch * HDIM * SEQ;

  for (int sp = 0; sp < 2; ++sp) {
    const int j = sp ? (127 - pi) : pi;  // strip: rows 16j..16j+15
    const int q0 = 16 * j;
    const int T64 = (j + 4) >> 2;  // ceil((j+1)/4) 64-key tiles
    const int nw = (T64 > w) ? (((T64 - 1 - w) >> 2) + 1) : 0;

    bf16x8 aq[2];
#pragma unroll
    for (int kf = 0; kf < 2; ++kf)
      aq[kf] = *reinterpret_cast<const bf16x8*>(
          qB + (size_t)(q0 + l16) * HDIM + 32 * kf + 8 * quad);

    v4f accO[4] = {};
    float l_part[4] = {0.f, 0.f, 0.f, 0.f};
    bf16x8 kfr[2][4][2];  // [slot][nt][kf] : 2-deep K prefetch

    auto loadK = [&](int jt, int slot) {
#pragma unroll
      for (int nt = 0; nt < 4; ++nt)
#pragma unroll
        for (int kf = 0; kf < 2; ++kf)
          kfr[slot][nt][kf] = *reinterpret_cast<const bf16x8*>(
              kB + (size_t)(64 * jt + 16 * nt + l16) * HDIM + 32 * kf +
              8 * quad);
    };
    auto qk_exp_stage = [&](int jt, int kslot, int pslot) {
      v4f s[4] = {};
#pragma unroll
      for (int nt = 0; nt < 4; ++nt) {
        s[nt] = MFMA_BF16(aq[0], kfr[kslot][nt][0], s[nt], 0, 0, 0);
        s[nt] = MFMA_BF16(aq[1], kfr[kslot][nt][1], s[nt], 0, 0, 0);
      }
      const bool last = (jt == T64 - 1);
#pragma unroll
      for (int nt = 0; nt < 4; ++nt)
#pragma unroll
        for (int r = 0; r < 4; ++r) {
          float p = __builtin_amdgcn_exp2f(s[nt][r] * SCALE_L2E);
          if (last && (64 * jt + 16 * nt + l16 > q0 + 4 * quad + r)) p = 0.f;
          l_part[r] += p;
          p_lds[w][pslot][4 * quad + r][16 * nt + l16] = (bf16)p;
        }
    };

    if (nw > 0) {
      loadK(w, 0);
      if (nw > 1) loadK(w + 4, 1);
      qk_exp_stage(w, 0, 0);
    }
    for (int i = 0; i < nw; ++i) {
      const int jt = w + 4 * i;
      if (i + 2 < nw) loadK(jt + 8, i & 1);  // K(i) slot is free now
      bf16x8 vfr[4][2];
#pragma unroll
      for (int nt = 0; nt < 4; ++nt)
#pragma unroll
        for (int kc = 0; kc < 2; ++kc)
          vfr[nt][kc] = *reinterpret_cast<const bf16x8*>(
              vB + (size_t)(16 * nt + l16) * SEQ + 64 * jt + 32 * kc +
              8 * quad);
      // p_lds[slot i&1] writes were issued one full iteration ago -> cheap
      asm volatile("s_waitcnt lgkmcnt(0)" ::: "memory");
      bf16x8 pa[2];
#pragma unroll
      for (int kc = 0; kc < 2; ++kc)
        pa[kc] = *reinterpret_cast<const bf16x8*>(
            &p_lds[w][i & 1][l16][32 * kc + 8 * quad]);
      // next stage's VALU (exp/cvt) covers vfr's L2 latency
      if (i + 1 < nw) qk_exp_stage(jt + 4, (i + 1) & 1, (i + 1) & 1);
#pragma unroll
      for (int nt = 0; nt < 4; ++nt) {
        accO[nt] = MFMA_BF16(pa[0], vfr[nt][0], accO[nt], 0, 0, 0);
        accO[nt] = MFMA_BF16(pa[1], vfr[nt][1], accO[nt], 0, 0, 0);
      }
    }

#pragma unroll
    for (int r = 0; r < 4; ++r) {
      float s = l_part[r];
      s += __shfl_xor(s, 1, 16);
      s += __shfl_xor(s, 2, 16);
      s += __shfl_xor(s, 4, 16);
      s += __shfl_xor(s, 8, 16);
      l_part[r] = s;
    }

    __syncthreads();  // prev strip's merge reads done before o_lds overwrite
    if (w > 0) {
#pragma unroll
      for (int nt = 0; nt < 4; ++nt)
#pragma unroll
        for (int r = 0; r < 4; ++r)
          o_lds[w - 1][4 * quad + r][16 * nt + l16] = accO[nt][r];
      if (l16 == 0) {
#pragma unroll
        for (int r = 0; r < 4; ++r) l_lds[w - 1][4 * quad + r] = l_part[r];
      }
    }
    __syncthreads();
    if (w == 0) {
#pragma unroll
      for (int r = 0; r < 4; ++r) {
        const int row = 4 * quad + r;
        float lt =
            l_part[r] + l_lds[0][row] + l_lds[1][row] + l_lds[2][row];
        float inv = 1.0f / lt;
        float* op = out + ((size_t)batch * SEQ + q0 + row) * HDIM;
#pragma unroll
        for (int nt = 0; nt < 4; ++nt)
          op[16 * nt + l16] =
              (accO[nt][r] + o_lds[0][row][16 * nt + l16] +
               o_lds[1][row][16 * nt + l16] + o_lds[2][row][16 * nt + l16]) *
              inv;
      }
    }
  }
}

// ---------------- launcher -------------------------------------------------
extern "C" void kernel_launch(void* const* d_in, const int* in_sizes, int n_in,
                              void* d_out, int out_size, void* d_ws,
                              size_t ws_size, hipStream_t stream) {
  const float* x = (const float*)d_in[0];
  const float* Wq = (const float*)d_in[1];
  const float* Wk = (const float*)d_in[2];
  const float* Wv = (const float*)d_in[3];

  char* ws = (char*)d_ws;
  bf16* Wt = (bf16*)(ws);
  bf16* qw = (bf16*)(ws + 0x60000);
  bf16* kw = (bf16*)(ws + 0x260000);
  bf16* vT = (bf16*)(ws + 0x460000);

  prep_w_kernel<<<96, 256, 0, stream>>>(Wq, Wk, Wv, Wt);
  proj_kernel<<<512, 256, 0, stream>>>(x, Wt, qw, kw, vT);
  attn_kernel<<<512, 256, 0, stream>>>(qw, kw, vT, (float*)d_out);
}

// Round 5
// 171.147 us; speedup vs baseline: 1.0373x; 1.0373x over previous
//
#include <hip/hip_runtime.h>

// ---------------------------------------------------------------------------
// CausalSelfAttentionHead: B=8, S=2048, E=1024, H=64, scale = 1/H (NOT 1/sqrt)
// k0 prep_w : W fp32 [1024][64] -> Wt bf16 [192][1024]
// k1 proj   : ZERO-LDS, ZERO-BARRIER GEMM. Wave owns 16 rows x all N=192.
//             A-frags direct from x (k-contiguous, lines fully used, 2-deep
//             prefetch), B-frags direct from L2-resident Wt (2-deep).
//             All reg-array indices compile-time (r4's spill lesson).
// k2 attn   : r3's proven pipeline at M=16: strips paired (j,127-j), grid 512
//             (2 blocks/CU), single-buffer K regs (STATIC indices), 2-slot
//             p_lds transpose, no max-subtraction (scores bounded), deferred
//             l-reduction, batch=blockIdx&7 for XCD-local K/V.
// ws: Wt @0, qw @0x60000, kw @0x260000, vT @0x460000 (6.4MB total)
// ---------------------------------------------------------------------------

typedef __bf16 bf16;
typedef bf16 bf16x8 __attribute__((ext_vector_type(8)));
typedef bf16 bf16x4 __attribute__((ext_vector_type(4)));
typedef float v4f __attribute__((ext_vector_type(4)));

#define MFMA_BF16 __builtin_amdgcn_mfma_f32_16x16x32_bf16

constexpr int SEQ = 2048, EDIM = 1024, HDIM = 64;
constexpr float SCALE_L2E = 1.4426950408889634f / 64.0f;  // log2(e)/head_size

// ---------------- kernel 0: weight transpose + cvt -------------------------
__global__ __launch_bounds__(256) void prep_w_kernel(
    const float* __restrict__ Wq, const float* __restrict__ Wk,
    const float* __restrict__ Wv, bf16* __restrict__ Wt) {
  int mat = blockIdx.x >> 5, kseg = blockIdx.x & 31;
  const float* src = mat == 0 ? Wq : (mat == 1 ? Wk : Wv);
  int n = threadIdx.x & 63;
  int k0 = kseg * 32 + (threadIdx.x >> 6) * 8;
  bf16x8 v;
#pragma unroll
  for (int j = 0; j < 8; ++j)
    v[j] = (bf16)src[(k0 + j) * 64 + n];
  *reinterpret_cast<bf16x8*>(Wt + (size_t)(mat * 64 + n) * EDIM + k0) = v;
}

// ---------------- kernel 1: barrier-free QKV projection --------------------
// grid 256 (BM=64), block 256; wave w owns rows m0+16w..+15, all 192 N-cols.
__global__ __launch_bounds__(256) void proj_kernel(
    const float* __restrict__ x, const bf16* __restrict__ Wt,
    bf16* __restrict__ qw, bf16* __restrict__ kw, bf16* __restrict__ vT) {
  const int t = threadIdx.x;
  const int w = t >> 6, lane = t & 63, quad = lane >> 4, l16 = lane & 15;
  const int m0 = blockIdx.x * 64;
  const int row = m0 + 16 * w + l16;  // this lane's A row (= MFMA m index)

  const float* xr = x + (size_t)row * EDIM + 8 * quad;
  const bf16* wB = Wt + (size_t)l16 * EDIM + 8 * quad;

  v4f acc[12] = {};
  float4 aA[2][4];    // [chunk-parity][ks*2 + half]; 2-chunk-deep A prefetch
  bf16x8 bReg[2][12]; // [chunk-parity][3*g + ni -> 2*ni+ks]; 2-chunk-deep B

  auto loadA = [&](int kk, int slot) {
    const float* p = xr + kk * 64;
    aA[slot][0] = *reinterpret_cast<const float4*>(p);
    aA[slot][1] = *reinterpret_cast<const float4*>(p + 4);
    aA[slot][2] = *reinterpret_cast<const float4*>(p + 32);
    aA[slot][3] = *reinterpret_cast<const float4*>(p + 36);
  };
  auto loadB = [&](int kk, int slot) {
#pragma unroll
    for (int nt = 0; nt < 6; ++nt)
#pragma unroll
      for (int ks = 0; ks < 2; ++ks)
        bReg[slot][2 * nt + ks] = *reinterpret_cast<const bf16x8*>(
            wB + (size_t)(16 * nt) * EDIM + kk * 64 + 32 * ks);
  };
  // note: bReg[s][2*nt+ks] covers n-tiles 0..5; tiles 6..11 via second set
  bf16x8 bReg2[2][12];
  auto loadB2 = [&](int kk, int slot) {
#pragma unroll
    for (int nt = 0; nt < 6; ++nt)
#pragma unroll
      for (int ks = 0; ks < 2; ++ks)
        bReg2[slot][2 * nt + ks] = *reinterpret_cast<const bf16x8*>(
            wB + (size_t)(16 * (nt + 6)) * EDIM + kk * 64 + 32 * ks);
  };

  loadA(0, 0);
  loadB(0, 0);
  loadB2(0, 0);
  loadA(1, 1);
  loadB(1, 1);
  loadB2(1, 1);

#pragma unroll 2
  for (int kk = 0; kk < 16; ++kk) {
    const int buf = kk & 1;
    // cvt this chunk's A (loaded 2 chunks ago) to bf16 fragments
    bf16x8 af[2];
#pragma unroll
    for (int ks = 0; ks < 2; ++ks) {
      float4 lo = aA[buf][2 * ks], hi = aA[buf][2 * ks + 1];
      af[ks][0] = (bf16)lo.x; af[ks][1] = (bf16)lo.y;
      af[ks][2] = (bf16)lo.z; af[ks][3] = (bf16)lo.w;
      af[ks][4] = (bf16)hi.x; af[ks][5] = (bf16)hi.y;
      af[ks][6] = (bf16)hi.z; af[ks][7] = (bf16)hi.w;
    }
    if (kk + 2 < 16) loadA(kk + 2, buf);  // aA[buf] regs free after cvt
#pragma unroll
    for (int nt = 0; nt < 6; ++nt)
#pragma unroll
      for (int ks = 0; ks < 2; ++ks)
        acc[nt] = MFMA_BF16(af[ks], bReg[buf][2 * nt + ks], acc[nt], 0, 0, 0);
#pragma unroll
    for (int nt = 0; nt < 6; ++nt)
#pragma unroll
      for (int ks = 0; ks < 2; ++ks)
        acc[6 + nt] =
            MFMA_BF16(af[ks], bReg2[buf][2 * nt + ks], acc[6 + nt], 0, 0, 0);
    // refill B for kk+2 AFTER its slot's last use (in flight across kk+1)
    if (kk + 2 < 16) {
      loadB(kk + 2, buf);
      loadB2(kk + 2, buf);
    }
  }

  // epilogue: C/D row = 4*quad+r (token), col = l16 (n within tile)
  const int token0 = m0 + 16 * w + 4 * quad;
#pragma unroll
  for (int tl = 0; tl < 12; ++tl) {
    if (tl < 4) {
      const int n = 16 * tl + l16;
#pragma unroll
      for (int r = 0; r < 4; ++r)
        qw[(size_t)(token0 + r) * HDIM + n] = (bf16)acc[tl][r];
    } else if (tl < 8) {
      const int n = 16 * (tl - 4) + l16;
#pragma unroll
      for (int r = 0; r < 4; ++r)
        kw[(size_t)(token0 + r) * HDIM + n] = (bf16)acc[tl][r];
    } else {
      const int hrow = 16 * (tl - 8) + l16;
      const int b = token0 >> 11, s0 = token0 & 2047;
      bf16x4 pk = {(bf16)acc[tl][0], (bf16)acc[tl][1], (bf16)acc[tl][2],
                   (bf16)acc[tl][3]};
      *reinterpret_cast<bf16x4*>(vT + ((size_t)(b * 64 + hrow)) * SEQ + s0) =
          pk;
    }
  }
}

// ---------------- kernel 2: pipelined flash attention (M=16) ---------------
// grid 512 = 64 strip-pairs x 8 batches; block 256 = 4 waves;
// wave w takes 64-key tiles jt == w (mod 4). Single-buffer K regs (static
// indices only — r4's runtime-indexed regs spilled to scratch).
__global__ __launch_bounds__(256) void attn_kernel(
    const bf16* __restrict__ qw, const bf16* __restrict__ kw,
    const bf16* __restrict__ vT, float* __restrict__ out) {
  const int batch = blockIdx.x & 7;
  const int pi = blockIdx.x >> 3;  // 0..63
  const int w = threadIdx.x >> 6;
  const int lane = threadIdx.x & 63;
  const int quad = lane >> 4, l16 = lane & 15;

  __shared__ __align__(16) bf16 p_lds[4][2][16][68];
  __shared__ __align__(16) float o_lds[3][16][68];
  __shared__ float l_lds[3][16];

  const bf16* qB = qw + (size_t)batch * SEQ * HDIM;
  const bf16* kB = kw + (size_t)batch * SEQ * HDIM;
  const bf16* vB = vT + (size_t)batch * HDIM * SEQ;

  for (int sp = 0; sp < 2; ++sp) {
    const int j = sp ? (127 - pi) : pi;  // strip: rows 16j..16j+15
    const int q0 = 16 * j;
    const int T64 = (j >> 2) + 1;  // # of 64-key tiles (causal)
    const int nw = (T64 > w) ? (((T64 - 1 - w) >> 2) + 1) : 0;

    bf16x8 aq[2];
#pragma unroll
    for (int kf = 0; kf < 2; ++kf)
      aq[kf] = *reinterpret_cast<const bf16x8*>(
          qB + (size_t)(q0 + l16) * HDIM + 32 * kf + 8 * quad);

    v4f accO[4] = {};
    float l_part[4] = {0.f, 0.f, 0.f, 0.f};
    bf16x8 kfr[4][2];  // single buffer, static indices only

    auto loadK = [&](int jt) {
#pragma unroll
      for (int nt = 0; nt < 4; ++nt)
#pragma unroll
        for (int kf = 0; kf < 2; ++kf)
          kfr[nt][kf] = *reinterpret_cast<const bf16x8*>(
              kB + (size_t)(64 * jt + 16 * nt + l16) * HDIM + 32 * kf +
              8 * quad);
    };
    auto qk_exp_stage = [&](int jt, int pslot) {
      v4f s[4] = {};
#pragma unroll
      for (int nt = 0; nt < 4; ++nt) {
        s[nt] = MFMA_BF16(aq[0], kfr[nt][0], s[nt], 0, 0, 0);
        s[nt] = MFMA_BF16(aq[1], kfr[nt][1], s[nt], 0, 0, 0);
      }
      const bool last = (jt == T64 - 1);
#pragma unroll
      for (int nt = 0; nt < 4; ++nt)
#pragma unroll
        for (int r = 0; r < 4; ++r) {
          float p = __builtin_amdgcn_exp2f(s[nt][r] * SCALE_L2E);
          if (last && (64 * jt + 16 * nt + l16 > q0 + 4 * quad + r)) p = 0.f;
          l_part[r] += p;
          p_lds[w][pslot][4 * quad + r][16 * nt + l16] = (bf16)p;
        }
    };

    if (nw > 0) {
      loadK(w);
      qk_exp_stage(w, 0);
    }
    for (int i = 0; i < nw; ++i) {
      const int jt = w + 4 * i;
      if (i + 1 < nw) loadK(jt + 4);  // overwrites kfr; prev QK already done
      bf16x8 vfr[4][2];
#pragma unroll
      for (int nt = 0; nt < 4; ++nt)
#pragma unroll
        for (int kc = 0; kc < 2; ++kc)
          vfr[nt][kc] = *reinterpret_cast<const bf16x8*>(
              vB + (size_t)(16 * nt + l16) * SEQ + 64 * jt + 32 * kc +
              8 * quad);
      // p_lds[slot i&1] writes were issued one full iteration ago -> cheap
      asm volatile("s_waitcnt lgkmcnt(0)" ::: "memory");
      bf16x8 pa[2];
#pragma unroll
      for (int kc = 0; kc < 2; ++kc)
        pa[kc] = *reinterpret_cast<const bf16x8*>(
            &p_lds[w][i & 1][l16][32 * kc + 8 * quad]);
      // next stage's QK/exp covers vfr's L2 latency
      if (i + 1 < nw) qk_exp_stage(jt + 4, (i + 1) & 1);
#pragma unroll
      for (int nt = 0; nt < 4; ++nt) {
        accO[nt] = MFMA_BF16(pa[0], vfr[nt][0], accO[nt], 0, 0, 0);
        accO[nt] = MFMA_BF16(pa[1], vfr[nt][1], accO[nt], 0, 0, 0);
      }
    }

    // deferred l reduction over the 16 key-lanes
#pragma unroll
    for (int r = 0; r < 4; ++r) {
      float s = l_part[r];
      s += __shfl_xor(s, 1, 16);
      s += __shfl_xor(s, 2, 16);
      s += __shfl_xor(s, 4, 16);
      s += __shfl_xor(s, 8, 16);
      l_part[r] = s;
    }

    __syncthreads();  // prev strip's merge reads done before o_lds overwrite
    if (w > 0) {
#pragma unroll
      for (int nt = 0; nt < 4; ++nt)
#pragma unroll
        for (int r = 0; r < 4; ++r)
          o_lds[w - 1][4 * quad + r][16 * nt + l16] = accO[nt][r];
      if (l16 == 0) {
#pragma unroll
        for (int r = 0; r < 4; ++r) l_lds[w - 1][4 * quad + r] = l_part[r];
      }
    }
    __syncthreads();
    if (w == 0) {
#pragma unroll
      for (int r = 0; r < 4; ++r) {
        const int row = 4 * quad + r;
        float lt = l_part[r] + l_lds[0][row] + l_lds[1][row] + l_lds[2][row];
        float inv = 1.0f / lt;
        float* op = out + ((size_t)batch * SEQ + q0 + row) * HDIM;
#pragma unroll
        for (int nt = 0; nt < 4; ++nt)
          op[16 * nt + l16] =
              (accO[nt][r] + o_lds[0][row][16 * nt + l16] +
               o_lds[1][row][16 * nt + l16] + o_lds[2][row][16 * nt + l16]) *
              inv;
      }
    }
  }
}

// ---------------- launcher -------------------------------------------------
extern "C" void kernel_launch(void* const* d_in, const int* in_sizes, int n_in,
                              void* d_out, int out_size, void* d_ws,
                              size_t ws_size, hipStream_t stream) {
  const float* x = (const float*)d_in[0];
  const float* Wq = (const float*)d_in[1];
  const float* Wk = (const float*)d_in[2];
  const float* Wv = (const float*)d_in[3];

  char* ws = (char*)d_ws;
  bf16* Wt = (bf16*)(ws);
  bf16* qw = (bf16*)(ws + 0x60000);
  bf16* kw = (bf16*)(ws + 0x260000);
  bf16* vT = (bf16*)(ws + 0x460000);

  prep_w_kernel<<<96, 256, 0, stream>>>(Wq, Wk, Wv, Wt);
  proj_kernel<<<256, 256, 0, stream>>>(x, Wt, qw, kw, vT);
  attn_kernel<<<512, 256, 0, stream>>>(qw, kw, vT, (float*)d_out);
}

// Round 6
// 168.031 us; speedup vs baseline: 1.0566x; 1.0185x over previous
//
#include <hip/hip_runtime.h>

// ---------------------------------------------------------------------------
// CausalSelfAttentionHead: B=8, S=2048, E=1024, H=64, scale = 1/H (NOT 1/sqrt)
// k0 prep_w : W fp32 [1024][64] -> Wt bf16 [192][1024]
// k1 proj   : barrier-free GEMM, wave = 16 rows x 96 cols (N-split by 2).
//             2048 waves = 8/CU = 2/SIMD (latency hiding; r5 had 1/SIMD).
//             Block = {2 m-strips}x{2 n-halves}: 32 KB unique/chunk = L1-shared.
//             A direct from x (k-contiguous, 2-deep), B direct from L2-resident
//             Wt (2-deep). All reg indices compile-time (r4 spill lesson).
// k2 attn   : r3's proven M=32 pipeline: strips paired (j,63-j), grid 256,
//             4 waves split K-tiles mod 4, 2-slot p_lds transpose, no
//             max-subtraction (scores bounded), deferred l-reduction.
// ws: Wt @0, qw @0x60000, kw @0x260000, vT @0x460000 (6.4MB total)
// ---------------------------------------------------------------------------

typedef __bf16 bf16;
typedef bf16 bf16x8 __attribute__((ext_vector_type(8)));
typedef bf16 bf16x4 __attribute__((ext_vector_type(4)));
typedef float v4f __attribute__((ext_vector_type(4)));

#define MFMA_BF16 __builtin_amdgcn_mfma_f32_16x16x32_bf16

constexpr int SEQ = 2048, EDIM = 1024, HDIM = 64;
constexpr float SCALE_L2E = 1.4426950408889634f / 64.0f;  // log2(e)/head_size

// ---------------- kernel 0: weight transpose + cvt -------------------------
__global__ __launch_bounds__(256) void prep_w_kernel(
    const float* __restrict__ Wq, const float* __restrict__ Wk,
    const float* __restrict__ Wv, bf16* __restrict__ Wt) {
  int mat = blockIdx.x >> 5, kseg = blockIdx.x & 31;
  const float* src = mat == 0 ? Wq : (mat == 1 ? Wk : Wv);
  int n = threadIdx.x & 63;
  int k0 = kseg * 32 + (threadIdx.x >> 6) * 8;
  bf16x8 v;
#pragma unroll
  for (int j = 0; j < 8; ++j)
    v[j] = (bf16)src[(k0 + j) * 64 + n];
  *reinterpret_cast<bf16x8*>(Wt + (size_t)(mat * 64 + n) * EDIM + k0) = v;
}

// ---------------- kernel 1: barrier-free QKV projection --------------------
// grid 512 (BM=32), block 256 = 4 waves: wave (mi = w&1, nh = w>>1) owns
// rows m0+16*mi..+15 and n-cols 96*nh..96*nh+95.
__global__ __launch_bounds__(256) void proj_kernel(
    const float* __restrict__ x, const bf16* __restrict__ Wt,
    bf16* __restrict__ qw, bf16* __restrict__ kw, bf16* __restrict__ vT) {
  const int t = threadIdx.x;
  const int w = t >> 6, lane = t & 63, quad = lane >> 4, l16 = lane & 15;
  const int mi = w & 1, nh = w >> 1;
  const int m0 = blockIdx.x * 32;
  const int row = m0 + 16 * mi + l16;  // this lane's A row (= MFMA m index)

  const float* xr = x + (size_t)row * EDIM + 8 * quad;
  const bf16* wB = Wt + (size_t)(96 * nh + l16) * EDIM + 8 * quad;

  v4f acc[6] = {};
  float4 aA[2][4];    // [chunk-parity][ks*2+half]: 2-chunk-deep A prefetch
  bf16x8 bReg[2][12]; // [chunk-parity][2*nt+ks]  : 2-chunk-deep B fragments

  auto loadA = [&](int kk, int slot) {
    const float* p = xr + kk * 64;
    aA[slot][0] = *reinterpret_cast<const float4*>(p);
    aA[slot][1] = *reinterpret_cast<const float4*>(p + 4);
    aA[slot][2] = *reinterpret_cast<const float4*>(p + 32);
    aA[slot][3] = *reinterpret_cast<const float4*>(p + 36);
  };
  auto loadB = [&](int kk, int slot) {
#pragma unroll
    for (int nt = 0; nt < 6; ++nt)
#pragma unroll
      for (int ks = 0; ks < 2; ++ks)
        bReg[slot][2 * nt + ks] = *reinterpret_cast<const bf16x8*>(
            wB + (size_t)(16 * nt) * EDIM + kk * 64 + 32 * ks);
  };

  loadA(0, 0);
  loadB(0, 0);
  loadA(1, 1);
  loadB(1, 1);

#pragma unroll 2
  for (int kk = 0; kk < 16; ++kk) {
    const int buf = kk & 1;
    bf16x8 af[2];  // cvt A chunk kk (loaded 2 chunks ago) to bf16 frags
#pragma unroll
    for (int ks = 0; ks < 2; ++ks) {
      float4 lo = aA[buf][2 * ks], hi = aA[buf][2 * ks + 1];
      af[ks][0] = (bf16)lo.x; af[ks][1] = (bf16)lo.y;
      af[ks][2] = (bf16)lo.z; af[ks][3] = (bf16)lo.w;
      af[ks][4] = (bf16)hi.x; af[ks][5] = (bf16)hi.y;
      af[ks][6] = (bf16)hi.z; af[ks][7] = (bf16)hi.w;
    }
    if (kk + 2 < 16) loadA(kk + 2, buf);  // aA[buf] free after cvt
#pragma unroll
    for (int nt = 0; nt < 6; ++nt)
#pragma unroll
      for (int ks = 0; ks < 2; ++ks)
        acc[nt] = MFMA_BF16(af[ks], bReg[buf][2 * nt + ks], acc[nt], 0, 0, 0);
    if (kk + 2 < 16) loadB(kk + 2, buf);  // slot free; in flight across kk+1
  }

  // epilogue: C/D row = 4*quad+r (token), col = l16 (n within 16-tile)
  const int token0 = m0 + 16 * mi + 4 * quad;
#pragma unroll
  for (int nt = 0; nt < 6; ++nt) {
    const int tl = 6 * nh + nt;  // global n-tile 0..11 (wave-uniform)
    if (tl < 4) {
      const int n = 16 * tl + l16;
#pragma unroll
      for (int r = 0; r < 4; ++r)
        qw[(size_t)(token0 + r) * HDIM + n] = (bf16)acc[nt][r];
    } else if (tl < 8) {
      const int n = 16 * (tl - 4) + l16;
#pragma unroll
      for (int r = 0; r < 4; ++r)
        kw[(size_t)(token0 + r) * HDIM + n] = (bf16)acc[nt][r];
    } else {
      const int hrow = 16 * (tl - 8) + l16;
      const int b = token0 >> 11, s0 = token0 & 2047;
      bf16x4 pk = {(bf16)acc[nt][0], (bf16)acc[nt][1], (bf16)acc[nt][2],
                   (bf16)acc[nt][3]};
      *reinterpret_cast<bf16x4*>(vT + ((size_t)(b * 64 + hrow)) * SEQ + s0) =
          pk;
    }
  }
}

// ---------------- kernel 2: pipelined flash attention (M=32, r3) -----------
// grid 256 = 32 strip-pairs x 8 batches; block 256 = 4 waves; 64-key tiles;
// wave w takes tiles jt == w (mod 4) of each strip.
__global__ __launch_bounds__(256) void attn_kernel(
    const bf16* __restrict__ qw, const bf16* __restrict__ kw,
    const bf16* __restrict__ vT, float* __restrict__ out) {
  const int batch = blockIdx.x & 7;
  const int pi = blockIdx.x >> 3;  // 0..31
  const int w = threadIdx.x >> 6;
  const int lane = threadIdx.x & 63;
  const int quad = lane >> 4, l16 = lane & 15;

  __shared__ __align__(16) bf16 p_lds[4][2][32][68];  // [wave][slot][row][key]
  __shared__ __align__(16) float o_lds[3][32][68];
  __shared__ float l_lds[3][32];

  const bf16* qB = qw + (size_t)batch * SEQ * HDIM;
  const bf16* kB = kw + (size_t)batch * SEQ * HDIM;
  const bf16* vB = vT + (size_t)batch * HDIM * SEQ;

  for (int sp = 0; sp < 2; ++sp) {
    const int j = sp ? (63 - pi) : pi;  // strip: rows 32j..32j+31
    const int q0 = 32 * j;
    const int T64 = (j + 2) >> 1;  // ceil((j+1)/2) 64-key tiles
    const int nw = (T64 > w) ? (((T64 - 1 - w) >> 2) + 1) : 0;

    bf16x8 aq[2][2];
#pragma unroll
    for (int mi = 0; mi < 2; ++mi)
#pragma unroll
      for (int kf = 0; kf < 2; ++kf)
        aq[mi][kf] = *reinterpret_cast<const bf16x8*>(
            qB + (size_t)(q0 + 16 * mi + l16) * HDIM + 32 * kf + 8 * quad);

    v4f accO[2][4] = {};
    float l_part[2][4] = {{0.f, 0.f, 0.f, 0.f}, {0.f, 0.f, 0.f, 0.f}};
    bf16x8 kfr[4][2];

    auto loadK = [&](int jt) {
#pragma unroll
      for (int nt = 0; nt < 4; ++nt)
#pragma unroll
        for (int kf = 0; kf < 2; ++kf)
          kfr[nt][kf] = *reinterpret_cast<const bf16x8*>(
              kB + (size_t)(64 * jt + 16 * nt + l16) * HDIM + 32 * kf +
              8 * quad);
    };
    auto qk_exp_stage = [&](int jt, int slot) {
      v4f s[2][4] = {};
#pragma unroll
      for (int mi = 0; mi < 2; ++mi)
#pragma unroll
        for (int nt = 0; nt < 4; ++nt) {
          s[mi][nt] = MFMA_BF16(aq[mi][0], kfr[nt][0], s[mi][nt], 0, 0, 0);
          s[mi][nt] = MFMA_BF16(aq[mi][1], kfr[nt][1], s[mi][nt], 0, 0, 0);
        }
      const bool last = (jt == T64 - 1);
#pragma unroll
      for (int mi = 0; mi < 2; ++mi)
#pragma unroll
        for (int nt = 0; nt < 4; ++nt)
#pragma unroll
          for (int r = 0; r < 4; ++r) {
            float p = __builtin_amdgcn_exp2f(s[mi][nt][r] * SCALE_L2E);
            if (last &&
                (64 * jt + 16 * nt + l16 > q0 + 16 * mi + 4 * quad + r))
              p = 0.f;
            l_part[mi][r] += p;
            p_lds[w][slot][16 * mi + 4 * quad + r][16 * nt + l16] = (bf16)p;
          }
    };

    if (nw > 0) {
      loadK(w);
      qk_exp_stage(w, 0);
    }
    for (int i = 0; i < nw; ++i) {
      const int jt = w + 4 * i;
      const int k0 = 64 * jt;
      if (i + 1 < nw) loadK(jt + 4);  // in flight across the drain
      bf16x8 vfr[4][2];
#pragma unroll
      for (int nt = 0; nt < 4; ++nt)
#pragma unroll
        for (int kc = 0; kc < 2; ++kc)
          vfr[nt][kc] = *reinterpret_cast<const bf16x8*>(
              vB + (size_t)(16 * nt + l16) * SEQ + k0 + 32 * kc + 8 * quad);
      // drain waits on slot(i&1) writes issued one full iteration ago -> cheap
      asm volatile("s_waitcnt lgkmcnt(0)" ::: "memory");
      bf16x8 pa[2][2];
#pragma unroll
      for (int mi = 0; mi < 2; ++mi)
#pragma unroll
        for (int kc = 0; kc < 2; ++kc)
          pa[mi][kc] = *reinterpret_cast<const bf16x8*>(
              &p_lds[w][i & 1][16 * mi + l16][32 * kc + 8 * quad]);
      if (i + 1 < nw) qk_exp_stage(jt + 4, (i + 1) & 1);  // overlaps PV below
#pragma unroll
      for (int mi = 0; mi < 2; ++mi)
#pragma unroll
        for (int nt = 0; nt < 4; ++nt) {
          accO[mi][nt] = MFMA_BF16(pa[mi][0], vfr[nt][0], accO[mi][nt], 0, 0, 0);
          accO[mi][nt] = MFMA_BF16(pa[mi][1], vfr[nt][1], accO[mi][nt], 0, 0, 0);
        }
    }

    // reduce l over the 16 key-lanes (deferred, once per strip)
#pragma unroll
    for (int mi = 0; mi < 2; ++mi)
#pragma unroll
      for (int r = 0; r < 4; ++r) {
        float s = l_part[mi][r];
        s += __shfl_xor(s, 1, 16);
        s += __shfl_xor(s, 2, 16);
        s += __shfl_xor(s, 4, 16);
        s += __shfl_xor(s, 8, 16);
        l_part[mi][r] = s;
      }

    __syncthreads();  // prev strip's merge reads done before o_lds overwrite
    if (w > 0) {
#pragma unroll
      for (int mi = 0; mi < 2; ++mi)
#pragma unroll
        for (int nt = 0; nt < 4; ++nt)
#pragma unroll
          for (int r = 0; r < 4; ++r)
            o_lds[w - 1][16 * mi + 4 * quad + r][16 * nt + l16] =
                accO[mi][nt][r];
      if (l16 == 0) {
#pragma unroll
        for (int mi = 0; mi < 2; ++mi)
#pragma unroll
          for (int r = 0; r < 4; ++r)
            l_lds[w - 1][16 * mi + 4 * quad + r] = l_part[mi][r];
      }
    }
    __syncthreads();
    if (w == 0) {
#pragma unroll
      for (int mi = 0; mi < 2; ++mi)
#pragma unroll
        for (int r = 0; r < 4; ++r) {
          const int row = 16 * mi + 4 * quad + r;
          float lt = l_part[mi][r] + l_lds[0][row] + l_lds[1][row] +
                     l_lds[2][row];
          float inv = 1.0f / lt;
          float* op = out + ((size_t)batch * SEQ + q0 + row) * HDIM;
#pragma unroll
          for (int nt = 0; nt < 4; ++nt)
            op[16 * nt + l16] =
                (accO[mi][nt][r] + o_lds[0][row][16 * nt + l16] +
                 o_lds[1][row][16 * nt + l16] +
                 o_lds[2][row][16 * nt + l16]) *
                inv;
        }
    }
  }
}

// ---------------- launcher -------------------------------------------------
extern "C" void kernel_launch(void* const* d_in, const int* in_sizes, int n_in,
                              void* d_out, int out_size, void* d_ws,
                              size_t ws_size, hipStream_t stream) {
  const float* x = (const float*)d_in[0];
  const float* Wq = (const float*)d_in[1];
  const float* Wk = (const float*)d_in[2];
  const float* Wv = (const float*)d_in[3];

  char* ws = (char*)d_ws;
  bf16* Wt = (bf16*)(ws);
  bf16* qw = (bf16*)(ws + 0x60000);
  bf16* kw = (bf16*)(ws + 0x260000);
  bf16* vT = (bf16*)(ws + 0x460000);

  prep_w_kernel<<<96, 256, 0, stream>>>(Wq, Wk, Wv, Wt);
  proj_kernel<<<512, 256, 0, stream>>>(x, Wt, qw, kw, vT);
  attn_kernel<<<256, 256, 0, stream>>>(qw, kw, vT, (float*)d_out);
}

// Round 7
// 144.488 us; speedup vs baseline: 1.2287x; 1.1629x over previous
//
#include <hip/hip_runtime.h>

// ---------------------------------------------------------------------------
// CausalSelfAttentionHead: B=8, S=2048, E=1024, H=64, scale = 1/H (NOT 1/sqrt)
// Lesson r6: direct-from-global MFMA fragment loads scatter 16 rows/instr
// (~64 L1 transactions each) -> TA-throughput-bound. Fix: fragment-order
// pre-layouts + wave-private LDS bounce, all loads contiguous.
// k0 prep_w : W fp32 -> WtF bf16 in MFMA fragment order
//             [kk 0..15][ntl 0..11][ks 0..1][lane 0..63] x 8 elems
// k1 proj   : barrier-free. Wave = 16 rows x 96 cols. A: coalesced global ->
//             reg cvt -> wave-PRIVATE LDS slot (no __syncthreads ever) ->
//             fragment ds_read. B: contiguous 1KB loads from WtF. 2-deep pipe.
// k2 swz    : K,V -> fragment order (once; attn re-reads each ~48x coalesced)
// k3 attn   : r6/r3 proven pipeline, loads now contiguous from kswz/vswz.
// ws: WtF @0 (384K), qw @0x60000, kw @0x260000, vT @0x460000,
//     kswz @0x660000, vswz @0x860000  (10.4 MB total)
// ---------------------------------------------------------------------------

typedef __bf16 bf16;
typedef bf16 bf16x8 __attribute__((ext_vector_type(8)));
typedef bf16 bf16x4 __attribute__((ext_vector_type(4)));
typedef float v4f __attribute__((ext_vector_type(4)));

#define MFMA_BF16 __builtin_amdgcn_mfma_f32_16x16x32_bf16

constexpr int SEQ = 2048, EDIM = 1024, HDIM = 64;
constexpr float SCALE_L2E = 1.4426950408889634f / 64.0f;  // log2(e)/head_size

// ---------------- kernel 0: weights -> fragment layout ---------------------
// frag f = kk*24 + ntl*2 + ks; element addr = (f*64 + lane)*8.
__global__ __launch_bounds__(256) void prep_w_kernel(
    const float* __restrict__ Wq, const float* __restrict__ Wk,
    const float* __restrict__ Wv, bf16* __restrict__ WtF) {
  const int tg = blockIdx.x * 256 + threadIdx.x;  // 24576 = 384 frags x 64
  const int lane = tg & 63, f = tg >> 6;
  const int kk = f / 24, rem = f % 24, ntl = rem >> 1, ks = rem & 1;
  const int q = lane >> 4, l16 = lane & 15;
  const float* src = (ntl < 4) ? Wq : ((ntl < 8) ? Wk : Wv);
  const int n = (ntl & 3) * 16 + l16;
  const int k0 = kk * 64 + 32 * ks + 8 * q;
  bf16x8 v;
#pragma unroll
  for (int j = 0; j < 8; ++j) v[j] = (bf16)src[(k0 + j) * 64 + n];
  *reinterpret_cast<bf16x8*>(WtF + (size_t)tg * 8) = v;
}

// ---------------- kernel 1: barrier-free QKV projection --------------------
// grid 512 (BM=32), block 256 = 4 waves: wave (mi=w&1, nh=w>>1) owns rows
// m0+16*mi..+15, n-cols 96*nh..+95. Wave-private LDS A slot -> no barriers.
__global__ __launch_bounds__(256, 2) void proj_kernel(
    const float* __restrict__ x, const bf16* __restrict__ WtF,
    bf16* __restrict__ qw, bf16* __restrict__ kw, bf16* __restrict__ vT) {
  __shared__ __align__(16) bf16 As[2][4][16][72];  // [buf][wave][row][col]

  const int t = threadIdx.x;
  const int w = t >> 6, lane = t & 63, quad = lane >> 4, l16 = lane & 15;
  const int mi = w & 1, nh = w >> 1;
  const int m0 = blockIdx.x * 32;

  // A staging: lane covers row lane>>2 (of wave's 16), cols (lane&3)*16..+16
  const int srow = lane >> 2, scol = (lane & 3) * 16;
  const float* xs = x + (size_t)(m0 + 16 * mi + srow) * EDIM + scol;

  v4f acc[6] = {};
  float4 aReg[2][2];   // [slot][half]: 16 floats = lane's staging piece
  bf16x8 bReg[2][12];  // [slot][2*nt+ks]

  auto loadA = [&](int kk, int slot) {
    const float* p = xs + kk * 64;
    aReg[slot][0] = *reinterpret_cast<const float4*>(p);
    aReg[slot][1] = *reinterpret_cast<const float4*>(p + 4);
    // second 8 floats of the 16: scol+8..15
    // (use two more float4s? 16 floats needed) -> handled below via p+8
  };
  // NOTE: lane stages 16 bf16 = 16 floats; need 4 float4. Keep 2x float4 pairs:
  float4 aReg2[2][2];
  auto loadA2 = [&](int kk, int slot) {
    const float* p = xs + kk * 64 + 8;
    aReg2[slot][0] = *reinterpret_cast<const float4*>(p);
    aReg2[slot][1] = *reinterpret_cast<const float4*>(p + 4);
  };
  auto loadB = [&](int kk, int slot) {
#pragma unroll
    for (int nt = 0; nt < 6; ++nt)
#pragma unroll
      for (int ks = 0; ks < 2; ++ks)
        bReg[slot][2 * nt + ks] = *reinterpret_cast<const bf16x8*>(
            WtF +
            (size_t)((kk * 24 + (6 * nh + nt) * 2 + ks) * 64 + lane) * 8);
  };
  auto commitA = [&](int slot, int buf) {  // chunk in aReg[slot] -> As[buf][w]
    bf16x8 h0, h1;
#pragma unroll
    for (int e = 0; e < 4; ++e) {
      h0[e] = (bf16)(&aReg[slot][0].x)[e];
      h0[4 + e] = (bf16)(&aReg[slot][1].x)[e];
      h1[e] = (bf16)(&aReg2[slot][0].x)[e];
      h1[4 + e] = (bf16)(&aReg2[slot][1].x)[e];
    }
    *reinterpret_cast<bf16x8*>(&As[buf][w][srow][scol]) = h0;
    *reinterpret_cast<bf16x8*>(&As[buf][w][srow][scol + 8]) = h1;
  };

  loadA(0, 0); loadA2(0, 0); loadB(0, 0);
  loadA(1, 1); loadA2(1, 1); loadB(1, 1);
  commitA(0, 0);

#pragma unroll 2
  for (int kk = 0; kk < 16; ++kk) {
    const int buf = kk & 1;
    bf16x8 af[2];
#pragma unroll
    for (int ks = 0; ks < 2; ++ks)
      af[ks] = *reinterpret_cast<const bf16x8*>(
          &As[buf][w][l16][32 * ks + 8 * quad]);
    if (kk + 2 < 16) { loadA(kk + 2, buf); loadA2(kk + 2, buf); }
#pragma unroll
    for (int nt = 0; nt < 6; ++nt)
#pragma unroll
      for (int ks = 0; ks < 2; ++ks)
        acc[nt] = MFMA_BF16(af[ks], bReg[buf][2 * nt + ks], acc[nt], 0, 0, 0);
    if (kk + 2 < 16) loadB(kk + 2, buf);
    if (kk + 1 < 16) commitA(buf ^ 1, buf ^ 1);  // chunk kk+1 -> other buf
  }

  // epilogue: C/D row = 4*quad+r (token), col = l16 (n within 16-tile)
  const int token0 = m0 + 16 * mi + 4 * quad;
#pragma unroll
  for (int nt = 0; nt < 6; ++nt) {
    const int tl = 6 * nh + nt;  // global n-tile (wave-uniform)
    if (tl < 4) {
      const int n = 16 * tl + l16;
#pragma unroll
      for (int r = 0; r < 4; ++r)
        qw[(size_t)(token0 + r) * HDIM + n] = (bf16)acc[nt][r];
    } else if (tl < 8) {
      const int n = 16 * (tl - 4) + l16;
#pragma unroll
      for (int r = 0; r < 4; ++r)
        kw[(size_t)(token0 + r) * HDIM + n] = (bf16)acc[nt][r];
    } else {
      const int hrow = 16 * (tl - 8) + l16;
      const int b = token0 >> 11, s0 = token0 & 2047;
      bf16x4 pk = {(bf16)acc[nt][0], (bf16)acc[nt][1], (bf16)acc[nt][2],
                   (bf16)acc[nt][3]};
      *reinterpret_cast<bf16x4*>(vT + ((size_t)(b * 64 + hrow)) * SEQ + s0) =
          pk;
    }
  }
}

// ---------------- kernel 2: K,V -> fragment layout -------------------------
// Per batch: frag id (jt*8 + nt*2 + kf), addr = (id*64+lane)*8 (131072 elems).
__global__ __launch_bounds__(256) void swz_kernel(
    const bf16* __restrict__ kw, const bf16* __restrict__ vT,
    bf16* __restrict__ kswz, bf16* __restrict__ vswz) {
  const int batch = blockIdx.x & 7;
  const int jt = blockIdx.x >> 3;  // 0..31
  const int t = threadIdx.x, lane = t & 63;
  const int q = lane >> 4, l16 = lane & 15;
  const bf16* kB = kw + (size_t)batch * SEQ * HDIM;
  const bf16* vB = vT + (size_t)batch * HDIM * SEQ;
  bf16* kS = kswz + (size_t)batch * 131072;
  bf16* vS = vswz + (size_t)batch * 131072;
#pragma unroll
  for (int rep = 0; rep < 4; ++rep) {
    const int fi = rep * 4 + (t >> 6);  // 0..15
    const int nt = (fi & 7) >> 1, h = fi & 1;
    bf16x8 v;
    if (fi < 8)  // K frag: row 64jt+16nt+l16, cols 32h+8q..+8
      v = *reinterpret_cast<const bf16x8*>(
          kB + (size_t)(64 * jt + 16 * nt + l16) * HDIM + 32 * h + 8 * q);
    else  // V frag: vT row 16nt+l16 (head), cols 64jt+32h+8q (seq)
      v = *reinterpret_cast<const bf16x8*>(
          vB + (size_t)(16 * nt + l16) * SEQ + 64 * jt + 32 * h + 8 * q);
    bf16* dst = (fi < 8) ? kS : vS;
    *reinterpret_cast<bf16x8*>(
        dst + (size_t)((jt * 8 + nt * 2 + h) * 64 + lane) * 8) = v;
  }
}

// ---------------- kernel 3: pipelined flash attention (M=32) ---------------
// grid 256 = 32 strip-pairs x 8 batches; block 256 = 4 waves; 64-key tiles;
// wave w takes tiles jt == w (mod 4). K/V loads contiguous from swizzle.
__global__ __launch_bounds__(256) void attn_kernel(
    const bf16* __restrict__ qw, const bf16* __restrict__ kswz,
    const bf16* __restrict__ vswz, float* __restrict__ out) {
  const int batch = blockIdx.x & 7;
  const int pi = blockIdx.x >> 3;  // 0..31
  const int w = threadIdx.x >> 6;
  const int lane = threadIdx.x & 63;
  const int quad = lane >> 4, l16 = lane & 15;

  __shared__ __align__(16) bf16 p_lds[4][2][32][68];
  __shared__ __align__(16) float o_lds[3][32][68];
  __shared__ float l_lds[3][32];

  const bf16* qB = qw + (size_t)batch * SEQ * HDIM;
  const bf16* kS = kswz + (size_t)batch * 131072;
  const bf16* vS = vswz + (size_t)batch * 131072;

  for (int sp = 0; sp < 2; ++sp) {
    const int j = sp ? (63 - pi) : pi;  // strip: rows 32j..32j+31
    const int q0 = 32 * j;
    const int T64 = (j + 2) >> 1;
    const int nw = (T64 > w) ? (((T64 - 1 - w) >> 2) + 1) : 0;

    bf16x8 aq[2][2];
#pragma unroll
    for (int mi = 0; mi < 2; ++mi)
#pragma unroll
      for (int kf = 0; kf < 2; ++kf)
        aq[mi][kf] = *reinterpret_cast<const bf16x8*>(
            qB + (size_t)(q0 + 16 * mi + l16) * HDIM + 32 * kf + 8 * quad);

    v4f accO[2][4] = {};
    float l_part[2][4] = {{0.f, 0.f, 0.f, 0.f}, {0.f, 0.f, 0.f, 0.f}};
    bf16x8 kfr[4][2];

    auto loadK = [&](int jt) {
#pragma unroll
      for (int nt = 0; nt < 4; ++nt)
#pragma unroll
        for (int kf = 0; kf < 2; ++kf)
          kfr[nt][kf] = *reinterpret_cast<const bf16x8*>(
              kS + (size_t)((jt * 8 + nt * 2 + kf) * 64 + lane) * 8);
    };
    auto qk_exp_stage = [&](int jt, int slot) {
      v4f s[2][4] = {};
#pragma unroll
      for (int mi = 0; mi < 2; ++mi)
#pragma unroll
        for (int nt = 0; nt < 4; ++nt) {
          s[mi][nt] = MFMA_BF16(aq[mi][0], kfr[nt][0], s[mi][nt], 0, 0, 0);
          s[mi][nt] = MFMA_BF16(aq[mi][1], kfr[nt][1], s[mi][nt], 0, 0, 0);
        }
      const bool last = (jt == T64 - 1);
#pragma unroll
      for (int mi = 0; mi < 2; ++mi)
#pragma unroll
        for (int nt = 0; nt < 4; ++nt)
#pragma unroll
          for (int r = 0; r < 4; ++r) {
            float p = __builtin_amdgcn_exp2f(s[mi][nt][r] * SCALE_L2E);
            if (last &&
                (64 * jt + 16 * nt + l16 > q0 + 16 * mi + 4 * quad + r))
              p = 0.f;
            l_part[mi][r] += p;
            p_lds[w][slot][16 * mi + 4 * quad + r][16 * nt + l16] = (bf16)p;
          }
    };

    if (nw > 0) {
      loadK(w);
      qk_exp_stage(w, 0);
    }
    for (int i = 0; i < nw; ++i) {
      const int jt = w + 4 * i;
      if (i + 1 < nw) loadK(jt + 4);
      bf16x8 vfr[4][2];
#pragma unroll
      for (int nt = 0; nt < 4; ++nt)
#pragma unroll
        for (int kc = 0; kc < 2; ++kc)
          vfr[nt][kc] = *reinterpret_cast<const bf16x8*>(
              vS + (size_t)((jt * 8 + nt * 2 + kc) * 64 + lane) * 8);
      asm volatile("s_waitcnt lgkmcnt(0)" ::: "memory");
      bf16x8 pa[2][2];
#pragma unroll
      for (int mi = 0; mi < 2; ++mi)
#pragma unroll
        for (int kc = 0; kc < 2; ++kc)
          pa[mi][kc] = *reinterpret_cast<const bf16x8*>(
              &p_lds[w][i & 1][16 * mi + l16][32 * kc + 8 * quad]);
      if (i + 1 < nw) qk_exp_stage(jt + 4, (i + 1) & 1);
#pragma unroll
      for (int mi = 0; mi < 2; ++mi)
#pragma unroll
        for (int nt = 0; nt < 4; ++nt) {
          accO[mi][nt] = MFMA_BF16(pa[mi][0], vfr[nt][0], accO[mi][nt], 0, 0, 0);
          accO[mi][nt] = MFMA_BF16(pa[mi][1], vfr[nt][1], accO[mi][nt], 0, 0, 0);
        }
    }

#pragma unroll
    for (int mi = 0; mi < 2; ++mi)
#pragma unroll
      for (int r = 0; r < 4; ++r) {
        float s = l_part[mi][r];
        s += __shfl_xor(s, 1, 16);
        s += __shfl_xor(s, 2, 16);
        s += __shfl_xor(s, 4, 16);
        s += __shfl_xor(s, 8, 16);
        l_part[mi][r] = s;
      }

    __syncthreads();
    if (w > 0) {
#pragma unroll
      for (int mi = 0; mi < 2; ++mi)
#pragma unroll
        for (int nt = 0; nt < 4; ++nt)
#pragma unroll
          for (int r = 0; r < 4; ++r)
            o_lds[w - 1][16 * mi + 4 * quad + r][16 * nt + l16] =
                accO[mi][nt][r];
      if (l16 == 0) {
#pragma unroll
        for (int mi = 0; mi < 2; ++mi)
#pragma unroll
          for (int r = 0; r < 4; ++r)
            l_lds[w - 1][16 * mi + 4 * quad + r] = l_part[mi][r];
      }
    }
    __syncthreads();
    if (w == 0) {
#pragma unroll
      for (int mi = 0; mi < 2; ++mi)
#pragma unroll
        for (int r = 0; r < 4; ++r) {
          const int row = 16 * mi + 4 * quad + r;
          float lt = l_part[mi][r] + l_lds[0][row] + l_lds[1][row] +
                     l_lds[2][row];
          float inv = 1.0f / lt;
          float* op = out + ((size_t)batch * SEQ + q0 + row) * HDIM;
#pragma unroll
          for (int nt = 0; nt < 4; ++nt)
            op[16 * nt + l16] =
                (accO[mi][nt][r] + o_lds[0][row][16 * nt + l16] +
                 o_lds[1][row][16 * nt + l16] +
                 o_lds[2][row][16 * nt + l16]) *
                inv;
        }
    }
  }
}

// ---------------- launcher -------------------------------------------------
extern "C" void kernel_launch(void* const* d_in, const int* in_sizes, int n_in,
                              void* d_out, int out_size, void* d_ws,
                              size_t ws_size, hipStream_t stream) {
  const float* x = (const float*)d_in[0];
  const float* Wq = (const float*)d_in[1];
  const float* Wk = (const float*)d_in[2];
  const float* Wv = (const float*)d_in[3];

  char* ws = (char*)d_ws;
  bf16* WtF = (bf16*)(ws);
  bf16* qw = (bf16*)(ws + 0x60000);
  bf16* kw = (bf16*)(ws + 0x260000);
  bf16* vT = (bf16*)(ws + 0x460000);
  bf16* kswz = (bf16*)(ws + 0x660000);
  bf16* vswz = (bf16*)(ws + 0x860000);

  prep_w_kernel<<<96, 256, 0, stream>>>(Wq, Wk, Wv, WtF);
  proj_kernel<<<512, 256, 0, stream>>>(x, WtF, qw, kw, vT);
  swz_kernel<<<256, 256, 0, stream>>>(kw, vT, kswz, vswz);
  attn_kernel<<<256, 256, 0, stream>>>(qw, kswz, vswz, (float*)d_out);
}